// Round 1
// 1101.388 us; speedup vs baseline: 1.1467x; 1.1467x over previous
//
#include <hip/hip_runtime.h>
#include <hip/hip_bf16.h>
#include <cstdint>
#include <cstddef>

// B=128, S=512, D=768, H=12, DH=64. Attention over BATCH axis: 6144 heads
// (s,h), seq-len 128, head-dim 64. Mask is inverted-causal (j<=i masked).
//
// R4 changes vs R3 (R3 post-mortem: gemm_qkv at 19.5% MfmaUtil, nothing
// saturated -> 2-barrier-per-K-step structure is the ceiling (m233: ~72%
// of critical path is stage+vmcnt(0)+barrier drain)):
//  - Both GEMMs -> 256x256 tile, BK=64, 8 waves (2Mx4N), double-buffered
//    128 KiB LDS, 4 phases per K-tile with counted s_waitcnt vmcnt(2) at
//    K-tile boundaries only (T3+T4), raw s_barrier (no __syncthreads drain),
//    s_setprio(1) around each 16-MFMA cluster (T5).
//  - Subtiled LDS layout (16x32 bf16 = 1024B per subtile, staged by
//    global_load_lds lane order) is conflict-free (R2 measured 0) -> T2
//    precondition satisfied without swizzle.
//  - Grid: n-tile index fastest -> A m-tile (384 KB) + whole B (<=3.4 MB)
//    stay hot in XCD L2; A read ~once from HBM instead of 9x/18x.
//  - Buffer hazard schedule: all ds_reads of K-tile t done by end of ph3;
//    prefetch of t+2 into buf[t&1] occupies slots ph4(t)..ph3(t+1); one
//    vmcnt(2) before ph4-end barrier guarantees t+1 landed (prologue:
//    10 loads issued, vmcnt(2) = t0's 8 landed).

typedef __attribute__((ext_vector_type(8))) short bf16x8_t;
typedef __attribute__((ext_vector_type(4))) float f32x4_t;

__device__ inline unsigned short f2bf(float x) {
  union { float f; unsigned int u; } v; v.f = x;
  return (unsigned short)((v.u + 0x7FFFu + ((v.u >> 16) & 1u)) >> 16);  // RNE
}

#define GLL16(gp, lp) __builtin_amdgcn_global_load_lds(                      \
    (const __attribute__((address_space(1))) void*)(gp),                     \
    (__attribute__((address_space(3))) void*)(lp), 16, 0, 0)

// raw barrier with compiler memory fence, WITHOUT the vmcnt(0)/lgkmcnt(0)
// drain that __syncthreads() emits.
__device__ __forceinline__ void bar() {
  asm volatile("" ::: "memory");
  __builtin_amdgcn_s_barrier();
  asm volatile("" ::: "memory");
}
#define WAITV(n) asm volatile("s_waitcnt vmcnt(" #n ")" ::: "memory")

// ---------------------------------------------------------------- fp32->bf16
__global__ __launch_bounds__(256) void cvt_kernel(const float* __restrict__ in,
                                                  unsigned short* __restrict__ out,
                                                  int n4) {
  int i = blockIdx.x * 256 + threadIdx.x;
  if (i >= n4) return;
  const float4 v = ((const float4*)in)[i];
  ushort4 o;
  o.x = f2bf(v.x); o.y = f2bf(v.y); o.z = f2bf(v.z); o.w = f2bf(v.w);
  ((ushort4*)out)[i] = o;
}

__global__ void bias_tail(const float* __restrict__ b, float* __restrict__ out) {
  int i = blockIdx.x * 256 + threadIdx.x;
  if (i < 768) out[(size_t)128 * 512 * 768 + i] = b[i];
}

// ------------------------------------------------------------- 256^2 GEMM
// C[M x N] = A[M x 768] * Bt[N x 768]^T (+bias, bf16 out) or fp32 out.
// K = 768 = 12 K-tiles of BK=64. Grid: (N/256, M/256), x (n) fastest.
// 8 waves: wm = wave>>2 (2), wn = wave&3 (4); per-wave C = 128 x 64.
// LDS per matrix per buffer: 32 subtiles x 1024B = 32 KB; 2 matrices x
// 2 buffers = 128 KB. Subtile = 16 rows x 32 k (staged as lane*16B by
// GLL16; frag read at lane*16B is conflict-free).
template <bool BF16OUT>
__global__ __launch_bounds__(512, 2) void gemm256(
    const unsigned short* __restrict__ A,
    const unsigned short* __restrict__ Bt,
    const float* __restrict__ bias,
    unsigned short* __restrict__ outB,
    float* __restrict__ outF,
    const int ldo) {
  __shared__ unsigned short As[2 * 16384];   // [buf][32 subtiles][512]
  __shared__ unsigned short Bs[2 * 16384];

  const int tid = threadIdx.x;
  const int wave = tid >> 6, lane = tid & 63;
  const int lane15 = lane & 15, quad = lane >> 4;
  const int wm = wave >> 2, wn = wave & 3;
  const int mBase = blockIdx.y * 256;
  const int nBase = blockIdx.x * 256;

  f32x4_t acc[8][4];
#pragma unroll
  for (int i = 0; i < 8; ++i)
#pragma unroll
    for (int j = 0; j < 4; ++j) { f32x4_t z = {0.f, 0.f, 0.f, 0.f}; acc[i][j] = z; }

  // staging: wave stages A rowgroups {2w,2w+1} and B rowgroups {2w,2w+1}.
  // GLL16 lane l -> row (l&15), k-chunk (l>>4) of a 16x32 subtile.
  const unsigned short* Ag = A + (size_t)(mBase + wave * 32 + lane15) * 768 + quad * 8;
  const unsigned short* Bg = Bt + (size_t)(nBase + wave * 32 + lane15) * 768 + quad * 8;

#define STAGE_A(t_, ro_) do {                                                 \
    const unsigned short* s_ = Ag + (size_t)(ro_) * (16 * 768) + (t_) * 64;   \
    unsigned short* d_ = &As[(((t_) & 1) << 14) + (2 * wave + (ro_)) * 1024]; \
    GLL16(s_, d_); GLL16(s_ + 32, d_ + 512);                                  \
  } while (0)
#define STAGE_B(t_, ro_) do {                                                 \
    const unsigned short* s_ = Bg + (size_t)(ro_) * (16 * 768) + (t_) * 64;   \
    unsigned short* d_ = &Bs[(((t_) & 1) << 14) + (2 * wave + (ro_)) * 1024]; \
    GLL16(s_, d_); GLL16(s_ + 32, d_ + 512);                                  \
  } while (0)

  // frag bases: subtile (rg*2 + kk), rg = wm*8+im (A) / wn*4+in (B)
  const unsigned short* aB = &As[(wm * 8) * 1024 + lane * 8];
  const unsigned short* bB = &Bs[(wn * 4) * 1024 + lane * 8];
#define RA(buf_, im_, kk_) (*(const bf16x8_t*)&aB[(buf_) + ((im_) * 2 + (kk_)) * 512])
#define RB(buf_, in_, kk_) (*(const bf16x8_t*)&bB[(buf_) + ((in_) * 2 + (kk_)) * 512])

  // ---- prologue: all of t0 (8 loads) + t1 slot0 (2 loads)
  STAGE_A(0, 0); STAGE_A(0, 1); STAGE_B(0, 0); STAGE_B(0, 1);
  STAGE_A(1, 0);
  WAITV(2);          // t0's 8 loads landed; t1.A(rg=2w) may stay in flight
  bar();

  const int NT = 12;
#pragma unroll 1
  for (int t = 0; t < NT; ++t) {
    const int buf = (t & 1) << 14;
    // ================= phase 1: kk0, mh0 =================
    bf16x8_t a0[4], b0[4];
#pragma unroll
    for (int im = 0; im < 4; ++im) a0[im] = RA(buf, im, 0);
#pragma unroll
    for (int in = 0; in < 4; ++in) b0[in] = RB(buf, in, 0);
    if (t + 1 < NT) STAGE_A(t + 1, 1);                 // slot1
    bar();
    __builtin_amdgcn_s_setprio(1);
#pragma unroll
    for (int im = 0; im < 4; ++im)
#pragma unroll
      for (int in = 0; in < 4; ++in)
        acc[im][in] = __builtin_amdgcn_mfma_f32_16x16x32_bf16(a0[im], b0[in], acc[im][in], 0, 0, 0);
    __builtin_amdgcn_s_setprio(0);
    bar();
    // ================= phase 2: kk0, mh1 (+ read kk1 frags) =================
    bf16x8_t a1[4], a0k[4], b1[4];
#pragma unroll
    for (int im = 0; im < 4; ++im) a1[im] = RA(buf, im + 4, 0);
#pragma unroll
    for (int im = 0; im < 4; ++im) a0k[im] = RA(buf, im, 1);
#pragma unroll
    for (int in = 0; in < 4; ++in) b1[in] = RB(buf, in, 1);
    if (t + 1 < NT) STAGE_B(t + 1, 0);                 // slot2
    bar();
    __builtin_amdgcn_s_setprio(1);
#pragma unroll
    for (int im = 0; im < 4; ++im)
#pragma unroll
      for (int in = 0; in < 4; ++in)
        acc[im + 4][in] = __builtin_amdgcn_mfma_f32_16x16x32_bf16(a1[im], b0[in], acc[im + 4][in], 0, 0, 0);
    __builtin_amdgcn_s_setprio(0);
    bar();
    // ================= phase 3: kk1, mh0 (last reads of buf) ================
    bf16x8_t a1k[4];
#pragma unroll
    for (int im = 0; im < 4; ++im) a1k[im] = RA(buf, im + 4, 1);
    if (t + 1 < NT) STAGE_B(t + 1, 1);                 // slot3
    bar();
    __builtin_amdgcn_s_setprio(1);
#pragma unroll
    for (int im = 0; im < 4; ++im)
#pragma unroll
      for (int in = 0; in < 4; ++in)
        acc[im][in] = __builtin_amdgcn_mfma_f32_16x16x32_bf16(a0k[im], b1[in], acc[im][in], 0, 0, 0);
    __builtin_amdgcn_s_setprio(0);
    bar();
    // ================= phase 4: kk1, mh1 (+ t+2 slot0, boundary wait) =======
    if (t + 2 < NT) STAGE_A(t + 2, 0);                 // slot0 for t+2
    bar();
    __builtin_amdgcn_s_setprio(1);
#pragma unroll
    for (int im = 0; im < 4; ++im)
#pragma unroll
      for (int in = 0; in < 4; ++in)
        acc[im + 4][in] = __builtin_amdgcn_mfma_f32_16x16x32_bf16(a1k[im], b1[in], acc[im + 4][in], 0, 0, 0);
    __builtin_amdgcn_s_setprio(0);
    if (t < NT - 1) {
      if (t + 2 < NT) { WAITV(2); } else { WAITV(0); } // t+1 fully landed
      bar();
    }
  }
#undef STAGE_A
#undef STAGE_B
#undef RA
#undef RB

  // ---- epilogue
  if constexpr (BF16OUT) {
    float bv[4];
#pragma unroll
    for (int in = 0; in < 4; ++in) bv[in] = bias[nBase + wn * 64 + in * 16 + lane15];
#pragma unroll
    for (int im = 0; im < 8; ++im) {
#pragma unroll
      for (int r = 0; r < 4; ++r) {
        const int m = mBase + wm * 128 + im * 16 + quad * 4 + r;
        unsigned short* orow = outB + (size_t)m * ldo + nBase + wn * 64 + lane15;
#pragma unroll
        for (int in = 0; in < 4; ++in)
          orow[in * 16] = f2bf(acc[im][in][r] + bv[in]);
      }
    }
  } else {
#pragma unroll
    for (int im = 0; im < 8; ++im) {
#pragma unroll
      for (int r = 0; r < 4; ++r) {
        const int m = mBase + wm * 128 + im * 16 + quad * 4 + r;
        float* orow = outF + (size_t)m * ldo + nBase + wn * 64 + lane15;
#pragma unroll
        for (int in = 0; in < 4; ++in)
          orow[in * 16] = acc[im][in][r];
      }
    }
  }
}

// ------------------------------------------------------- attention, 1 block/head
// LDS aliasing: V -> Ks region, P -> Qs region (both dead after QK^T phase).
__global__ __launch_bounds__(256) void attn_kernel(
    const unsigned short* __restrict__ QKV,   // [65536 x 2304] bf16
    unsigned short* __restrict__ Ctx) {       // [B,S,D] bf16
  __shared__ unsigned short Qs[128 * 72];     // 9216 elem; later Ps (needs 8704)
  __shared__ unsigned short Ks[128 * 72];     // 9216 elem; later Vt (needs 8704)

  const int n = blockIdx.x;         // head = s*12 + h
  const int s = n / 12;
  const int h = n - s * 12;
  const int tid = threadIdx.x;
  const int wave = tid >> 6, lane = tid & 63;
  const int lane15 = lane & 15, quad = lane >> 4;

  // ---- stage Q,K (128B contiguous per batch row)
#pragma unroll
  for (int it = 0; it < 4; ++it) {
    const int idx = it * 256 + tid;
    const int bb = idx >> 3, seg = idx & 7;
    const size_t g = (size_t)(bb * 512 + s) * 2304 + h * 192 + seg * 8;
    *(uint4*)&Qs[bb * 72 + seg * 8] = *(const uint4*)&QKV[g];
    *(uint4*)&Ks[bb * 72 + seg * 8] = *(const uint4*)&QKV[g + 64];
  }
  __syncthreads();

  // ---- QK^T: wave w -> score rows [w*32, w*32+32) x 128 cols
  f32x4_t sc[2][8];
#pragma unroll
  for (int im = 0; im < 2; ++im)
#pragma unroll
    for (int in = 0; in < 8; ++in) { f32x4_t z = {0.f, 0.f, 0.f, 0.f}; sc[im][in] = z; }

#pragma unroll
  for (int kk = 0; kk < 2; ++kk) {
    bf16x8_t a0 = *(const bf16x8_t*)&Qs[(wave * 32 + lane15) * 72 + kk * 32 + quad * 8];
    bf16x8_t a1 = *(const bf16x8_t*)&Qs[(wave * 32 + 16 + lane15) * 72 + kk * 32 + quad * 8];
#pragma unroll
    for (int in = 0; in < 8; ++in) {
      bf16x8_t b = *(const bf16x8_t*)&Ks[(in * 16 + lane15) * 72 + kk * 32 + quad * 8];
      sc[0][in] = __builtin_amdgcn_mfma_f32_16x16x32_bf16(a0, b, sc[0][in], 0, 0, 0);
      sc[1][in] = __builtin_amdgcn_mfma_f32_16x16x32_bf16(a1, b, sc[1][in], 0, 0, 0);
    }
  }
  __syncthreads();  // all Qs/Ks LDS reads complete -> regions reusable

  // ---- stage V transposed into Ks region; P will go into Qs region
  unsigned short* Vt = Ks;                    // [dh][c], stride 136
  unsigned short* Ps = Qs;                    // per-wave 16x136
  {
    const int c = tid & 127, half = tid >> 7;
    const size_t vb = (size_t)(c * 512 + s) * 2304 + h * 192 + 128;
#pragma unroll
    for (int dd = 0; dd < 4; ++dd) {
      const int dseg = half * 4 + dd;
      uint4 v = *(const uint4*)&QKV[vb + dseg * 8];
      const unsigned short* pv = (const unsigned short*)&v;
#pragma unroll
      for (int j = 0; j < 8; ++j) Vt[(dseg * 8 + j) * 136 + c] = pv[j];
    }
  }

  unsigned short* myP = Ps + wave * 16 * 136;

#pragma unroll 1
  for (int im = 0; im < 2; ++im) {
#pragma unroll
    for (int r = 0; r < 4; ++r) {
      const int row = wave * 32 + im * 16 + quad * 4 + r;
      float vals[8];
      float mx = -3.0e38f;
#pragma unroll
      for (int in = 0; in < 8; ++in) {
        const int col = in * 16 + lane15;
        float v = sc[im][in][r] * 0.125f;          // /sqrt(64)
        v = (col <= row) ? -10000.0f : v;          // inverted-causal mask
        vals[in] = v;
        mx = fmaxf(mx, v);
      }
      mx = fmaxf(mx, __shfl_xor(mx, 1, 16));
      mx = fmaxf(mx, __shfl_xor(mx, 2, 16));
      mx = fmaxf(mx, __shfl_xor(mx, 4, 16));
      mx = fmaxf(mx, __shfl_xor(mx, 8, 16));
      float sum = 0.f;
#pragma unroll
      for (int in = 0; in < 8; ++in) {
        const float e_ = __expf(vals[in] - mx);
        vals[in] = e_;
        sum += e_;
      }
      sum += __shfl_xor(sum, 1, 16);
      sum += __shfl_xor(sum, 2, 16);
      sum += __shfl_xor(sum, 4, 16);
      sum += __shfl_xor(sum, 8, 16);
      const float inv = 1.0f / sum;   // row 127: uniform 1/128, exact
#pragma unroll
      for (int in = 0; in < 8; ++in)
        myP[(quad * 4 + r) * 136 + in * 16 + lane15] = f2bf(vals[in] * inv);
    }
    __syncthreads();  // covers P writes + (im==0) V staging

    // P·V: 16 rows x 64 cols, K=128
    f32x4_t oc[4];
#pragma unroll
    for (int nt = 0; nt < 4; ++nt) { f32x4_t z = {0.f, 0.f, 0.f, 0.f}; oc[nt] = z; }
#pragma unroll
    for (int kk = 0; kk < 4; ++kk) {
      bf16x8_t a = *(const bf16x8_t*)&myP[lane15 * 136 + kk * 32 + quad * 8];
#pragma unroll
      for (int nt = 0; nt < 4; ++nt) {
        bf16x8_t b = *(const bf16x8_t*)&Vt[(nt * 16 + lane15) * 136 + kk * 32 + quad * 8];
        oc[nt] = __builtin_amdgcn_mfma_f32_16x16x32_bf16(a, b, oc[nt], 0, 0, 0);
      }
    }
#pragma unroll
    for (int nt = 0; nt < 4; ++nt) {
#pragma unroll
      for (int r = 0; r < 4; ++r) {
        const int bb = wave * 32 + im * 16 + quad * 4 + r;
        Ctx[((size_t)bb * 512 + s) * 768 + h * 64 + nt * 16 + lane15] = f2bf(oc[nt][r]);
      }
    }
    __syncthreads();
  }
}

// ---------------------------------------------------------------------- launch
extern "C" void kernel_launch(void* const* d_in, const int* in_sizes, int n_in,
                              void* d_out, int out_size, void* d_ws, size_t ws_size,
                              hipStream_t stream) {
  const float* X    = (const float*)d_in[0];   // [128,512,768]
  const float* Wqkv = (const float*)d_in[1];   // [2304,768]
  const float* bqkv = (const float*)d_in[2];   // [2304]
  const float* Wd   = (const float*)d_in[3];   // [768,768]
  const float* bd   = (const float*)d_in[4];   // [768]
  float* out = (float*)d_out;

  char* ws = (char*)d_ws;
  unsigned short* Xb  = (unsigned short*)(ws);                // 100,663,296 B (later: ctx)
  unsigned short* QKV = (unsigned short*)(ws + 100663296);    // [65536,2304] bf16
  unsigned short* Wqb = (unsigned short*)(ws + 402653184);
  unsigned short* Wdb = (unsigned short*)(ws + 406192128);

  cvt_kernel<<<dim3(49152), 256, 0, stream>>>(X, Xb, 12582912);
  cvt_kernel<<<dim3(1728), 256, 0, stream>>>(Wqkv, Wqb, 442368);
  cvt_kernel<<<dim3(576), 256, 0, stream>>>(Wd, Wdb, 147456);
  bias_tail<<<dim3(3), 256, 0, stream>>>(bd, out);

  gemm256<true><<<dim3(9, 256), 512, 0, stream>>>(Xb, Wqb, bqkv, QKV, nullptr, 2304);
  attn_kernel<<<dim3(6144), 256, 0, stream>>>(QKV, Xb /* ctx reuse */);
  gemm256<false><<<dim3(3, 256), 512, 0, stream>>>(Xb, Wdb, nullptr, nullptr, out, 768);
}